// Round 2
// baseline (185.046 us; speedup 1.0000x reference)
//
#include <hip/hip_runtime.h>

// (B,N,H,NB,NCT) = (8,4096,1024,128,33), H/2 = 512
#define NTOK 4096
#define HDIM 1024
#define HHALF 512
#define NBLK 128
#define MROWS 32768

typedef __attribute__((ext_vector_type(8))) short short8;
typedef __attribute__((ext_vector_type(4))) float f32x4;
typedef short bf16s;

__device__ __forceinline__ short f2bf(float f) {
    unsigned u = __builtin_bit_cast(unsigned, f);
    u = (u + 0x7fffu + ((u >> 16) & 1u)) >> 16;   // RNE
    return (short)u;
}
__device__ __forceinline__ float bf2f(short s) {
    unsigned u = ((unsigned)(unsigned short)s) << 16;
    return __builtin_bit_cast(float, u);
}
__device__ __forceinline__ void gload_lds16(const void* g, void* l) {
    __builtin_amdgcn_global_load_lds(
        (const __attribute__((address_space(1))) unsigned int*)g,
        (__attribute__((address_space(3))) unsigned int*)l, 16, 0, 0);
}

// ---------------------------------------------------------------------------
// Weight transpose+convert: w1t[n][k]=bf16(W1[k][n]) (n<512), wpt[n][k]=bf16(Wp[k][n])
// ---------------------------------------------------------------------------
__global__ void k_tcvt2(const float* __restrict__ W1, const float* __restrict__ Wp,
                        bf16s* __restrict__ w1t, bf16s* __restrict__ wpt) {
    size_t g = (size_t)blockIdx.x * 256 + threadIdx.x;
    if (g < (size_t)HHALF * 1024) {
        int n = (int)(g >> 10), k = (int)(g & 1023);
        w1t[g] = f2bf(W1[(size_t)k * HHALF + n]);
    } else {
        size_t h = g - (size_t)HHALF * 1024;
        if (h < (size_t)HDIM * 1024) {
            int n = (int)(h >> 10), k = (int)(h & 1023);
            wpt[h] = f2bf(Wp[(size_t)k * HDIM + n]);
        }
    }
}

// ---------------------------------------------------------------------------
// Gate GEMM: gate[row] = sum_c tanh((x@W1)[row][c]+b1[c])*W2[c] + b2
// M=32768, N=512(full per wg), K=1024. BM=128, BK=32, 512 thr = 8 waves (2x4).
// Wave tile 64x128, acc[4][8]. A: reg-staged f32->bf16 (prefetched), pad-40 LDS.
// B: global_load_lds w/ XOR-swizzled source -> conflict-free ds_read_b128.
// Side-writes bf16 x for the pooling kernel.
// ---------------------------------------------------------------------------
__global__ __launch_bounds__(512) void k_gemm_gate(
    const float* __restrict__ x, const bf16s* __restrict__ w1t,
    const float* __restrict__ b1, const float* __restrict__ w2,
    const float* __restrict__ b2, float* __restrict__ gate,
    bf16s* __restrict__ xb, int write_xb)
{
    __shared__ alignas(16) bf16s As[128 * 40];   // pad-40: 2-way conflicts only
    __shared__ alignas(16) bf16s Bs[512 * 32];   // linear (global_load_lds dest)
    __shared__ float gp[4][128];

    const int tid = threadIdx.x;
    const int lane = tid & 63;
    const int wv = tid >> 6;
    const int wr = wv >> 2, wc = wv & 3;
    const int row0 = blockIdx.x * 128;
    const int c0 = lane & 15, khalf = lane >> 4;
    const int ar = tid >> 2, seg = tid & 3;      // A staging: 128 rows x 4 segs(8 cols)

    const float* xrow = &x[(size_t)(row0 + ar) * HDIM + seg * 8];

    f32x4 acc[4][8] = {};

    float4 pa0 = *reinterpret_cast<const float4*>(xrow);
    float4 pa1 = *reinterpret_cast<const float4*>(xrow + 4);

    for (int kt = 0; kt < HDIM; kt += 32) {
        __syncthreads();                                     // prev compute done
        // stage A from prefetch regs
        short h[8] = {f2bf(pa0.x), f2bf(pa0.y), f2bf(pa0.z), f2bf(pa0.w),
                      f2bf(pa1.x), f2bf(pa1.y), f2bf(pa1.z), f2bf(pa1.w)};
        *reinterpret_cast<int4*>(&As[ar * 40 + seg * 8]) = *reinterpret_cast<const int4*>(h);
        // stage B: each wave 4 calls x 16 rows; source XOR-permuted so swizzled
        // layout lands via linear wave write (slot idx = j ^ ((c>>1)&3))
        #pragma unroll
        for (int q = 0; q < 4; ++q) {
            int c = wv * 64 + q * 16 + (lane >> 2);
            int j = (lane & 3) ^ ((c >> 1) & 3);
            gload_lds16(&w1t[(size_t)c * HDIM + kt + j * 8],
                        &Bs[(wv * 64 + q * 16) * 32 + lane * 8]);
        }
        __syncthreads();                                     // drains gll + ds_write
        // side-write bf16 x during compute phase (drains at next loop-top barrier)
        if (write_xb)
            *reinterpret_cast<int4*>(&xb[(size_t)(row0 + ar) * HDIM + kt + seg * 8]) =
                *reinterpret_cast<const int4*>(h);
        // prefetch next A f32 tile — latency hides under the 32-MFMA phase
        if (kt + 32 < HDIM) {
            pa0 = *reinterpret_cast<const float4*>(xrow + kt + 32);
            pa1 = *reinterpret_cast<const float4*>(xrow + kt + 36);
        }
        const int kk = khalf * 8;
        short8 av[4];
        #pragma unroll
        for (int mf = 0; mf < 4; ++mf)
            av[mf] = *reinterpret_cast<const short8*>(&As[(wr * 64 + mf * 16 + c0) * 40 + kk]);
        #pragma unroll
        for (int nf = 0; nf < 8; ++nf) {
            int cB = wc * 128 + nf * 16 + c0;
            int idx = khalf ^ ((cB >> 1) & 3);
            short8 bv = *reinterpret_cast<const short8*>(&Bs[cB * 32 + idx * 8]);
            #pragma unroll
            for (int mf = 0; mf < 4; ++mf)
                acc[mf][nf] = __builtin_amdgcn_mfma_f32_16x16x32_bf16(av[mf], bv, acc[mf][nf], 0, 0, 0);
        }
    }

    // epilogue: per-row reduce of tanh(h)*W2 over this wave's 128 cols
    #pragma unroll
    for (int mf = 0; mf < 4; ++mf) {
        #pragma unroll
        for (int reg = 0; reg < 4; ++reg) {
            float s = 0.f;
            #pragma unroll
            for (int nf = 0; nf < 8; ++nf) {
                int gc = wc * 128 + nf * 16 + c0;
                s += tanhf(acc[mf][nf][reg] + b1[gc]) * w2[gc];
            }
            s += __shfl_xor(s, 1); s += __shfl_xor(s, 2);
            s += __shfl_xor(s, 4); s += __shfl_xor(s, 8);
            if (c0 == 0) gp[wc][wr * 64 + mf * 16 + khalf * 4 + reg] = s;
        }
    }
    __syncthreads();
    if (tid < 128)
        gate[row0 + tid] = gp[0][tid] + gp[1][tid] + gp[2][tid] + gp[3][tid] + b2[0];
}

// ---------------------------------------------------------------------------
// Per-(b,block) masked softmax stats; writes has_b tail of d_out.
// ---------------------------------------------------------------------------
__global__ void k_stats(const int* __restrict__ block_ids, const unsigned char* __restrict__ pad,
                        const float* __restrict__ gate, const int* __restrict__ ct,
                        const float* __restrict__ ct_emb,
                        int* __restrict__ counts, float* __restrict__ mblk,
                        float* __restrict__ wscale, float* __restrict__ out_hasb)
{
    const int blk = blockIdx.x;
    const int b = blk >> 7, k = blk & 127;
    const int lane = threadIdx.x;
    const int base = b * NTOK;

    float m = -__builtin_inff();
    int cnt = 0;
    for (int t = lane; t < NTOK; t += 64) {
        bool mt = (block_ids[base + t] == k) && (pad[base + t] == 0);
        if (mt) { m = fmaxf(m, gate[base + t]); cnt++; }
    }
    #pragma unroll
    for (int off = 32; off; off >>= 1) {
        m = fmaxf(m, __shfl_xor(m, off));
        cnt += __shfl_xor(cnt, off);
    }
    float s = 0.f;
    for (int t = lane; t < NTOK; t += 64) {
        bool mt = (block_ids[base + t] == k) && (pad[base + t] == 0);
        if (mt) s += expf(gate[base + t] - m);
    }
    #pragma unroll
    for (int off = 32; off; off >>= 1) s += __shfl_xor(s, off);

    if (lane == 0) {
        counts[blk] = cnt;
        mblk[blk] = m;
        float mod = 1.0f + 0.1f * ct_emb[ct[b] * NBLK + k];
        wscale[blk] = (s > 0.f) ? (mod / fmaxf(s, 1e-30f)) : 0.f;
        out_hasb[blk] = (cnt > 0) ? 1.f : 0.f;
    }
}

// ---------------------------------------------------------------------------
// Member lists (CSR) with fused wave-parallel offset computation.
// ---------------------------------------------------------------------------
__global__ void k_fill(const int* __restrict__ block_ids, const unsigned char* __restrict__ pad,
                       const int* __restrict__ counts, int* __restrict__ offsets,
                       int* __restrict__ lists)
{
    const int blk = blockIdx.x;
    const int b = blk >> 7, k = blk & 127;
    const int lane = threadIdx.x;
    const int base = b * NTOK;

    int cA = counts[b * NBLK + lane];
    int cB = counts[b * NBLK + 64 + lane];
    int v = (lane < k ? cA : 0) + (64 + lane < k ? cB : 0);
    #pragma unroll
    for (int off = 32; off; off >>= 1) v += __shfl_xor(v, off);
    int pos = v;
    if (lane == 0) offsets[blk] = pos;

    for (int t0 = 0; t0 < NTOK; t0 += 64) {
        int t = t0 + lane;
        bool mt = (block_ids[base + t] == k) && (pad[base + t] == 0);
        unsigned long long mask = __ballot(mt);
        if (mt) {
            int my = __popcll(mask & ((1ull << lane) - 1ull));
            lists[base + pos + my] = t;
        }
        pos += __popcll(mask);
    }
}

// ---------------------------------------------------------------------------
// Pooling: pooled[b,k,:] = sum_n w_n * x[b,n,:]; reads bf16 x if available.
// ---------------------------------------------------------------------------
__global__ void k_pool(const float* __restrict__ x, const bf16s* __restrict__ xb, int use_bf,
                       const float* __restrict__ gate,
                       const int* __restrict__ lists, const int* __restrict__ counts,
                       const int* __restrict__ offsets, const float* __restrict__ mblk,
                       const float* __restrict__ wscale, bf16s* __restrict__ pooled)
{
    const int blk = blockIdx.x;
    const int b = blk >> 7;
    const int tid = threadIdx.x;
    const int base = b * NTOK;
    const int cnt = counts[blk];
    const int off = offsets[blk];
    const float m = mblk[blk], ws = wscale[blk];

    float4 acc = {0.f, 0.f, 0.f, 0.f};
    for (int i = 0; i < cnt; ++i) {
        int n = lists[base + off + i];
        float w = expf(gate[base + n] - m) * ws;
        float4 xv;
        if (use_bf) {
            int2 rv = *reinterpret_cast<const int2*>(&xb[(size_t)(base + n) * HDIM + tid * 4]);
            short s4[4];
            *reinterpret_cast<int2*>(s4) = rv;
            xv.x = bf2f(s4[0]); xv.y = bf2f(s4[1]); xv.z = bf2f(s4[2]); xv.w = bf2f(s4[3]);
        } else {
            xv = *reinterpret_cast<const float4*>(&x[(size_t)(base + n) * HDIM + tid * 4]);
        }
        acc.x += w * xv.x; acc.y += w * xv.y; acc.z += w * xv.z; acc.w += w * xv.w;
    }
    short o[4] = {f2bf(acc.x), f2bf(acc.y), f2bf(acc.z), f2bf(acc.w)};
    *reinterpret_cast<int2*>(&pooled[(size_t)blk * HDIM + tid * 4]) =
        *reinterpret_cast<const int2*>(o);
}

// ---------------------------------------------------------------------------
// GEMM2: y = pooled @ Wp + bp.  1024^3, 64x64 tiles, 4 waves.
// ---------------------------------------------------------------------------
__global__ void k_gemm2(const bf16s* __restrict__ pooled, const bf16s* __restrict__ wpt,
                        const float* __restrict__ bp, float* __restrict__ y)
{
    __shared__ alignas(16) bf16s As[64][40];
    __shared__ alignas(16) bf16s Bs[64][40];
    const int tid = threadIdx.x;
    const int lane = tid & 63;
    const int wv = tid >> 6;
    const int wr = wv >> 1, wc = wv & 1;
    const int row0 = (blockIdx.x >> 4) * 64, col0 = (blockIdx.x & 15) * 64;
    const int c0 = lane & 15, khalf = lane >> 4;
    const int sr = tid >> 2, sc = tid & 3;

    f32x4 acc[2][2] = {};
    for (int kt = 0; kt < 1024; kt += 32) {
        __syncthreads();
        *reinterpret_cast<int4*>(&As[sr][sc * 8]) =
            *reinterpret_cast<const int4*>(&pooled[(size_t)(row0 + sr) * 1024 + kt + sc * 8]);
        *reinterpret_cast<int4*>(&Bs[sr][sc * 8]) =
            *reinterpret_cast<const int4*>(&wpt[(size_t)(col0 + sr) * 1024 + kt + sc * 8]);
        __syncthreads();
        const int kk = khalf * 8;
        #pragma unroll
        for (int mf = 0; mf < 2; ++mf) {
            short8 av = *reinterpret_cast<const short8*>(&As[wr * 32 + mf * 16 + c0][kk]);
            #pragma unroll
            for (int nf = 0; nf < 2; ++nf) {
                short8 bv = *reinterpret_cast<const short8*>(&Bs[wc * 32 + nf * 16 + c0][kk]);
                acc[mf][nf] = __builtin_amdgcn_mfma_f32_16x16x32_bf16(av, bv, acc[mf][nf], 0, 0, 0);
            }
        }
    }
    #pragma unroll
    for (int mf = 0; mf < 2; ++mf)
        #pragma unroll
        for (int nf = 0; nf < 2; ++nf)
            #pragma unroll
            for (int reg = 0; reg < 4; ++reg) {
                int grow = row0 + wr * 32 + mf * 16 + khalf * 4 + reg;
                int gcol = col0 + wc * 32 + nf * 16 + c0;
                y[(size_t)grow * 1024 + gcol] = acc[mf][nf][reg] + bp[gcol];
            }
}

// ---------------------------------------------------------------------------
// LayerNorm + ELU + present-mask.
// ---------------------------------------------------------------------------
__global__ void k_lnelu(const float* __restrict__ y, const float* __restrict__ ln_g,
                        const float* __restrict__ ln_b, const int* __restrict__ counts,
                        float* __restrict__ outp)
{
    const int row = blockIdx.x;
    const int k = row & 127;
    const int tid = threadIdx.x;

    float4 v = *reinterpret_cast<const float4*>(&y[(size_t)row * 1024 + tid * 4]);
    float s = v.x + v.y + v.z + v.w;
    float ss = v.x * v.x + v.y * v.y + v.z * v.z + v.w * v.w;
    #pragma unroll
    for (int off = 32; off; off >>= 1) { s += __shfl_xor(s, off); ss += __shfl_xor(ss, off); }

    __shared__ float sbuf[4], ssbuf[4];
    int wv = tid >> 6;
    if ((tid & 63) == 0) { sbuf[wv] = s; ssbuf[wv] = ss; }
    __syncthreads();
    s = sbuf[0] + sbuf[1] + sbuf[2] + sbuf[3];
    ss = ssbuf[0] + ssbuf[1] + ssbuf[2] + ssbuf[3];

    float mu = s * (1.f / 1024.f);
    float var = ss * (1.f / 1024.f) - mu * mu;
    float rstd = rsqrtf(var + 1e-5f);

    bool pres = false;
    #pragma unroll
    for (int bb = 0; bb < 8; ++bb) pres = pres || (counts[bb * NBLK + k] > 0);

    float4 g4 = *reinterpret_cast<const float4*>(&ln_g[tid * 4]);
    float4 b4 = *reinterpret_cast<const float4*>(&ln_b[tid * 4]);
    float vals[4] = {v.x, v.y, v.z, v.w};
    float gs[4] = {g4.x, g4.y, g4.z, g4.w};
    float bs[4] = {b4.x, b4.y, b4.z, b4.w};
    float4 o;
    float* op = &o.x;
    #pragma unroll
    for (int j = 0; j < 4; ++j) {
        float t = (vals[j] - mu) * rstd * gs[j] + bs[j];
        t = (t > 0.f) ? t : expm1f(t);
        op[j] = pres ? t : 0.f;
    }
    *reinterpret_cast<float4*>(&outp[(size_t)row * 1024 + tid * 4]) = o;
}

// ---------------------------------------------------------------------------
extern "C" void kernel_launch(void* const* d_in, const int* in_sizes, int n_in,
                              void* d_out, int out_size, void* d_ws, size_t ws_size,
                              hipStream_t stream)
{
    const float* x      = (const float*)d_in[0];
    const int*   ct     = (const int*)d_in[1];
    const int*   bids   = (const int*)d_in[2];
    const unsigned char* pad = (const unsigned char*)d_in[3];
    const float* W1     = (const float*)d_in[4];
    const float* b1     = (const float*)d_in[5];
    const float* W2     = (const float*)d_in[6];
    const float* b2     = (const float*)d_in[7];
    const float* ct_emb = (const float*)d_in[8];
    const float* Wp     = (const float*)d_in[9];
    const float* bp     = (const float*)d_in[10];
    const float* ln_g   = (const float*)d_in[11];
    const float* ln_b   = (const float*)d_in[12];
    float* outF = (float*)d_out;

    char* ws = (char*)d_ws;
    bf16s* w1t    = (bf16s*)(ws + 0);          //  1,048,576
    bf16s* wpt    = (bf16s*)(ws + 1048576);    //  2,097,152
    float* gate   = (float*)(ws + 3145728);    //    131,072
    float* mblk   = (float*)(ws + 3276800);
    float* wscal  = (float*)(ws + 3280896);
    int*   counts = (int*)  (ws + 3284992);
    int*   offs   = (int*)  (ws + 3289088);
    int*   lists  = (int*)  (ws + 3293184);    //    131,072
    bf16s* pooled = (bf16s*)(ws + 3424256);    //  2,097,152
    float* ybuf   = (float*)(ws + 5521408);    //  4,194,304 -> ends 9,715,712
    bf16s* xb     = (bf16s*)(ws + 9715712);    // 67,108,864 -> ends 76,824,576
    const int use_xb = (ws_size >= 76824576ull) ? 1 : 0;

    k_tcvt2<<<6144, 256, 0, stream>>>(W1, Wp, w1t, wpt);
    k_gemm_gate<<<256, 512, 0, stream>>>(x, w1t, b1, W2, b2, gate, xb, use_xb);
    k_stats<<<1024, 64, 0, stream>>>(bids, pad, gate, ct, ct_emb, counts, mblk, wscal,
                                     outF + (size_t)8 * NBLK * HDIM);
    k_fill<<<1024, 64, 0, stream>>>(bids, pad, counts, offs, lists);
    k_pool<<<1024, 256, 0, stream>>>(x, xb, use_xb, gate, lists, counts, offs, mblk, wscal, pooled);
    k_gemm2<<<256, 256, 0, stream>>>(pooled, wpt, bp, ybuf);
    k_lnelu<<<1024, 256, 0, stream>>>(ybuf, ln_g, ln_b, counts, outF);
}

// Round 3
// 179.130 us; speedup vs baseline: 1.0330x; 1.0330x over previous
//
#include <hip/hip_runtime.h>

// (B,N,H,NB,NCT) = (8,4096,1024,128,33), H/2 = 512
#define NTOK 4096
#define HDIM 1024
#define HHALF 512
#define NBLK 128

typedef __attribute__((ext_vector_type(8))) short short8;
typedef __attribute__((ext_vector_type(4))) float f32x4;
typedef short bf16s;

__device__ __forceinline__ short f2bf(float f) {
    unsigned u = __builtin_bit_cast(unsigned, f);
    u = (u + 0x7fffu + ((u >> 16) & 1u)) >> 16;   // RNE
    return (short)u;
}
__device__ __forceinline__ float bf2f(short s) {
    unsigned u = ((unsigned)(unsigned short)s) << 16;
    return __builtin_bit_cast(float, u);
}
__device__ __forceinline__ void gload_lds16(const void* g, void* l) {
    __builtin_amdgcn_global_load_lds(
        (const __attribute__((address_space(1))) unsigned int*)g,
        (__attribute__((address_space(3))) unsigned int*)l, 16, 0, 0);
}
__device__ __forceinline__ float fast_tanh(float v) {
    // tanh(v) = 1 - 2/(e^{2v}+1); exact at +-inf saturation
    float e = __expf(2.0f * v);
    return 1.0f - 2.0f / (e + 1.0f);
}

// ---------------------------------------------------------------------------
// Tiled transpose+convert: out[n][k] = bf16(in[k][n]); K=1024, Nc mult of 64.
// ---------------------------------------------------------------------------
__global__ void k_tcvt(const float* __restrict__ in, bf16s* __restrict__ out, int Nc) {
    __shared__ float tile[64][65];
    const int k0 = blockIdx.x * 64;
    const int n0 = blockIdx.y * 64;
    const int tx = threadIdx.x & 63, ty = threadIdx.x >> 6;
    #pragma unroll
    for (int i = 0; i < 16; ++i) {
        int r = ty + i * 4;
        tile[r][tx] = in[(size_t)(k0 + r) * Nc + n0 + tx];
    }
    __syncthreads();
    #pragma unroll
    for (int i = 0; i < 16; ++i) {
        int r = ty + i * 4;
        out[(size_t)(n0 + r) * 1024 + k0 + tx] = f2bf(tile[tx][r]);
    }
}

// ---------------------------------------------------------------------------
// Gate GEMM: gate[row] = sum_c tanh((x@W1)[row][c]+b1[c])*W2[c] + b2
// M=32768, N=512(full), K=1024. BM=128, BK=32, 512 thr = 8 waves (2x4).
// Double-buffered LDS, ONE barrier per K-step; all loads issued pre-MFMA.
// Side-writes bf16 x (store-ack hidden under MFMA phase).
// ---------------------------------------------------------------------------
__global__ __launch_bounds__(512) void k_gemm_gate(
    const float* __restrict__ x, const bf16s* __restrict__ w1t,
    const float* __restrict__ b1, const float* __restrict__ w2,
    const float* __restrict__ b2, float* __restrict__ gate,
    bf16s* __restrict__ xb, int write_xb)
{
    __shared__ alignas(16) bf16s As[2][128 * 40];   // pad-40
    __shared__ alignas(16) bf16s Bs[2][512 * 32];   // linear dest, swizzled src
    __shared__ float gp[4][128];

    const int tid = threadIdx.x;
    const int lane = tid & 63;
    const int wv = tid >> 6;
    const int wr = wv >> 2, wc = wv & 3;
    const int row0 = blockIdx.x * 128;
    const int c0 = lane & 15, khalf = lane >> 4;
    const int ar = tid >> 2, seg = tid & 3;

    const float* xrow = &x[(size_t)(row0 + ar) * HDIM + seg * 8];
    bf16s* xbrow = write_xb ? &xb[(size_t)(row0 + ar) * HDIM + seg * 8] : nullptr;

    // B gll addressing (constant across iters except kt)
    const int bq_c[4] = {wv * 64 + 0 * 16 + (lane >> 2), wv * 64 + 1 * 16 + (lane >> 2),
                         wv * 64 + 2 * 16 + (lane >> 2), wv * 64 + 3 * 16 + (lane >> 2)};

    f32x4 acc[4][8] = {};

    // ---- prologue: tile 0 ----
    float4 pa0 = *reinterpret_cast<const float4*>(xrow);
    float4 pa1 = *reinterpret_cast<const float4*>(xrow + 4);
    {
        short h[8] = {f2bf(pa0.x), f2bf(pa0.y), f2bf(pa0.z), f2bf(pa0.w),
                      f2bf(pa1.x), f2bf(pa1.y), f2bf(pa1.z), f2bf(pa1.w)};
        *reinterpret_cast<int4*>(&As[0][ar * 40 + seg * 8]) = *reinterpret_cast<const int4*>(h);
        if (write_xb)
            *reinterpret_cast<int4*>(xbrow) = *reinterpret_cast<const int4*>(h);
        #pragma unroll
        for (int q = 0; q < 4; ++q) {
            int c = bq_c[q];
            int j = (lane & 3) ^ ((c >> 1) & 3);
            gload_lds16(&w1t[(size_t)c * HDIM + j * 8],
                        &Bs[0][(wv * 64 + q * 16) * 32 + lane * 8]);
        }
    }
    // prefetch A f32 for tile 1
    pa0 = *reinterpret_cast<const float4*>(xrow + 32);
    pa1 = *reinterpret_cast<const float4*>(xrow + 36);
    __syncthreads();

    // ---- main loop: one barrier per K-step ----
    for (int t = 0; t < 32; ++t) {
        const int cur = t & 1;
        const int kt_next = (t + 1) * 32;
        if (t < 31) {
            // issue next B tile (completes under MFMA phase)
            #pragma unroll
            for (int q = 0; q < 4; ++q) {
                int c = bq_c[q];
                int j = (lane & 3) ^ ((c >> 1) & 3);
                gload_lds16(&w1t[(size_t)c * HDIM + kt_next + j * 8],
                            &Bs[cur ^ 1][(wv * 64 + q * 16) * 32 + lane * 8]);
            }
            // convert prefetched A (resident since last iter), stage + side-write
            short h[8] = {f2bf(pa0.x), f2bf(pa0.y), f2bf(pa0.z), f2bf(pa0.w),
                          f2bf(pa1.x), f2bf(pa1.y), f2bf(pa1.z), f2bf(pa1.w)};
            *reinterpret_cast<int4*>(&As[cur ^ 1][ar * 40 + seg * 8]) =
                *reinterpret_cast<const int4*>(h);
            if (write_xb)
                *reinterpret_cast<int4*>(xbrow + kt_next) = *reinterpret_cast<const int4*>(h);
            if (t < 30) {
                pa0 = *reinterpret_cast<const float4*>(xrow + kt_next + 32);
                pa1 = *reinterpret_cast<const float4*>(xrow + kt_next + 36);
            }
        }
        // compute on buf[cur]
        const int kk = khalf * 8;
        short8 av[4];
        #pragma unroll
        for (int mf = 0; mf < 4; ++mf)
            av[mf] = *reinterpret_cast<const short8*>(
                &As[cur][(wr * 64 + mf * 16 + c0) * 40 + kk]);
        #pragma unroll
        for (int nf = 0; nf < 8; ++nf) {
            int cB = wc * 128 + nf * 16 + c0;
            int idx = khalf ^ ((cB >> 1) & 3);
            short8 bv = *reinterpret_cast<const short8*>(&Bs[cur][cB * 32 + idx * 8]);
            #pragma unroll
            for (int mf = 0; mf < 4; ++mf)
                acc[mf][nf] = __builtin_amdgcn_mfma_f32_16x16x32_bf16(av[mf], bv, acc[mf][nf], 0, 0, 0);
        }
        __syncthreads();
    }

    // ---- epilogue: per-row reduce of tanh(h)*W2 over this wave's 128 cols ----
    float b1v[8], w2v[8];
    #pragma unroll
    for (int nf = 0; nf < 8; ++nf) {
        int gc = wc * 128 + nf * 16 + c0;
        b1v[nf] = b1[gc];
        w2v[nf] = w2[gc];
    }
    #pragma unroll
    for (int mf = 0; mf < 4; ++mf) {
        #pragma unroll
        for (int reg = 0; reg < 4; ++reg) {
            float s = 0.f;
            #pragma unroll
            for (int nf = 0; nf < 8; ++nf)
                s += fast_tanh(acc[mf][nf][reg] + b1v[nf]) * w2v[nf];
            s += __shfl_xor(s, 1); s += __shfl_xor(s, 2);
            s += __shfl_xor(s, 4); s += __shfl_xor(s, 8);
            if (c0 == 0) gp[wc][wr * 64 + mf * 16 + khalf * 4 + reg] = s;
        }
    }
    __syncthreads();
    if (tid < 128)
        gate[row0 + tid] = gp[0][tid] + gp[1][tid] + gp[2][tid] + gp[3][tid] + b2[0];
}

// ---------------------------------------------------------------------------
// Per-(b,block) masked softmax stats; writes has_b tail of d_out.
// ---------------------------------------------------------------------------
__global__ void k_stats(const int* __restrict__ block_ids, const unsigned char* __restrict__ pad,
                        const float* __restrict__ gate, const int* __restrict__ ct,
                        const float* __restrict__ ct_emb,
                        int* __restrict__ counts, float* __restrict__ mblk,
                        float* __restrict__ wscale, float* __restrict__ out_hasb)
{
    const int blk = blockIdx.x;
    const int b = blk >> 7, k = blk & 127;
    const int lane = threadIdx.x;
    const int base = b * NTOK;

    float m = -__builtin_inff();
    int cnt = 0;
    for (int t = lane; t < NTOK; t += 64) {
        bool mt = (block_ids[base + t] == k) && (pad[base + t] == 0);
        if (mt) { m = fmaxf(m, gate[base + t]); cnt++; }
    }
    #pragma unroll
    for (int off = 32; off; off >>= 1) {
        m = fmaxf(m, __shfl_xor(m, off));
        cnt += __shfl_xor(cnt, off);
    }
    float s = 0.f;
    for (int t = lane; t < NTOK; t += 64) {
        bool mt = (block_ids[base + t] == k) && (pad[base + t] == 0);
        if (mt) s += expf(gate[base + t] - m);
    }
    #pragma unroll
    for (int off = 32; off; off >>= 1) s += __shfl_xor(s, off);

    if (lane == 0) {
        counts[blk] = cnt;
        mblk[blk] = m;
        float mod = 1.0f + 0.1f * ct_emb[ct[b] * NBLK + k];
        wscale[blk] = (s > 0.f) ? (mod / fmaxf(s, 1e-30f)) : 0.f;
        out_hasb[blk] = (cnt > 0) ? 1.f : 0.f;
    }
}

// ---------------------------------------------------------------------------
// Member lists (CSR) + precomputed per-member weights. Fused offsets.
// ---------------------------------------------------------------------------
__global__ void k_fill(const int* __restrict__ block_ids, const unsigned char* __restrict__ pad,
                       const int* __restrict__ counts, const float* __restrict__ gate,
                       const float* __restrict__ mblk, const float* __restrict__ wscale,
                       int* __restrict__ offsets, int* __restrict__ lists,
                       float* __restrict__ wlist)
{
    const int blk = blockIdx.x;
    const int b = blk >> 7, k = blk & 127;
    const int lane = threadIdx.x;
    const int base = b * NTOK;
    const float m = mblk[blk], ws = wscale[blk];

    int cA = counts[b * NBLK + lane];
    int cB = counts[b * NBLK + 64 + lane];
    int v = (lane < k ? cA : 0) + (64 + lane < k ? cB : 0);
    #pragma unroll
    for (int off = 32; off; off >>= 1) v += __shfl_xor(v, off);
    int pos = v;
    if (lane == 0) offsets[blk] = pos;

    for (int t0 = 0; t0 < NTOK; t0 += 64) {
        int t = t0 + lane;
        bool mt = (block_ids[base + t] == k) && (pad[base + t] == 0);
        unsigned long long mask = __ballot(mt);
        if (mt) {
            int my = __popcll(mask & ((1ull << lane) - 1ull));
            lists[base + pos + my] = t;
            wlist[base + pos + my] = __expf(gate[base + t] - m) * ws;
        }
        pos += __popcll(mask);
    }
}

// ---------------------------------------------------------------------------
// Pooling: pooled[b,k,:] = sum_n w_n * x[b,n,:] with precomputed w.
// ---------------------------------------------------------------------------
__global__ void k_pool(const float* __restrict__ x, const bf16s* __restrict__ xb, int use_bf,
                       const int* __restrict__ lists, const float* __restrict__ wlist,
                       const int* __restrict__ counts, const int* __restrict__ offsets,
                       bf16s* __restrict__ pooled)
{
    const int blk = blockIdx.x;
    const int b = blk >> 7;
    const int tid = threadIdx.x;
    const int base = b * NTOK;
    const int cnt = counts[blk];
    const int off = offsets[blk];

    float4 acc = {0.f, 0.f, 0.f, 0.f};
    for (int i = 0; i < cnt; ++i) {
        int n = lists[base + off + i];
        float w = wlist[base + off + i];
        float4 xv;
        if (use_bf) {
            int2 rv = *reinterpret_cast<const int2*>(&xb[(size_t)(base + n) * HDIM + tid * 4]);
            short s4[4];
            *reinterpret_cast<int2*>(s4) = rv;
            xv.x = bf2f(s4[0]); xv.y = bf2f(s4[1]); xv.z = bf2f(s4[2]); xv.w = bf2f(s4[3]);
        } else {
            xv = *reinterpret_cast<const float4*>(&x[(size_t)(base + n) * HDIM + tid * 4]);
        }
        acc.x += w * xv.x; acc.y += w * xv.y; acc.z += w * xv.z; acc.w += w * xv.w;
    }
    short o[4] = {f2bf(acc.x), f2bf(acc.y), f2bf(acc.z), f2bf(acc.w)};
    *reinterpret_cast<int2*>(&pooled[(size_t)blk * HDIM + tid * 4]) =
        *reinterpret_cast<const int2*>(o);
}

// ---------------------------------------------------------------------------
// GEMM2: y = pooled @ Wp + bp. 1024^3. 64x64 tiles, 4 waves (2x2), BK=32.
// Double-buffered, gll both operands, one barrier per K-step.
// ---------------------------------------------------------------------------
__global__ __launch_bounds__(256) void k_gemm2(
    const bf16s* __restrict__ pooled, const bf16s* __restrict__ wpt,
    const float* __restrict__ bp, float* __restrict__ y)
{
    __shared__ alignas(16) bf16s As[2][64 * 32];
    __shared__ alignas(16) bf16s Bs[2][64 * 32];
    const int tid = threadIdx.x;
    const int lane = tid & 63;
    const int wv = tid >> 6;
    const int wr = wv >> 1, wc = wv & 1;
    const int row0 = (blockIdx.x >> 4) * 64, col0 = (blockIdx.x & 15) * 64;
    const int c0 = lane & 15, khalf = lane >> 4;

    const int sr = wv * 16 + (lane >> 2);          // tile-local staged row
    const int sj = (lane & 3) ^ ((sr >> 1) & 3);   // swizzled source chunk
    const int sdst = (wv * 16) * 32 + lane * 8;    // linear LDS dest (shorts)
    const bf16s* srcA = &pooled[(size_t)(row0 + sr) * 1024 + sj * 8];
    const bf16s* srcB = &wpt[(size_t)(col0 + sr) * 1024 + sj * 8];

    f32x4 acc[2][2] = {};

    gload_lds16(srcA, &As[0][sdst]);
    gload_lds16(srcB, &Bs[0][sdst]);
    __syncthreads();

    for (int t = 0; t < 32; ++t) {
        const int cur = t & 1;
        if (t < 31) {
            gload_lds16(srcA + (t + 1) * 32, &As[cur ^ 1][sdst]);
            gload_lds16(srcB + (t + 1) * 32, &Bs[cur ^ 1][sdst]);
        }
        #pragma unroll
        for (int mf = 0; mf < 2; ++mf) {
            int ra = wr * 32 + mf * 16 + c0;
            short8 av = *reinterpret_cast<const short8*>(
                &As[cur][ra * 32 + ((khalf ^ ((ra >> 1) & 3)) * 8)]);
            #pragma unroll
            for (int nf = 0; nf < 2; ++nf) {
                int rb = wc * 32 + nf * 16 + c0;
                short8 bv = *reinterpret_cast<const short8*>(
                    &Bs[cur][rb * 32 + ((khalf ^ ((rb >> 1) & 3)) * 8)]);
                acc[mf][nf] = __builtin_amdgcn_mfma_f32_16x16x32_bf16(av, bv, acc[mf][nf], 0, 0, 0);
            }
        }
        __syncthreads();
    }
    #pragma unroll
    for (int mf = 0; mf < 2; ++mf)
        #pragma unroll
        for (int nf = 0; nf < 2; ++nf)
            #pragma unroll
            for (int reg = 0; reg < 4; ++reg) {
                int grow = row0 + wr * 32 + mf * 16 + khalf * 4 + reg;
                int gcol = col0 + wc * 32 + nf * 16 + c0;
                y[(size_t)grow * 1024 + gcol] = acc[mf][nf][reg] + bp[gcol];
            }
}

// ---------------------------------------------------------------------------
// LayerNorm + ELU + present-mask.
// ---------------------------------------------------------------------------
__global__ void k_lnelu(const float* __restrict__ y, const float* __restrict__ ln_g,
                        const float* __restrict__ ln_b, const int* __restrict__ counts,
                        float* __restrict__ outp)
{
    const int row = blockIdx.x;
    const int k = row & 127;
    const int tid = threadIdx.x;

    float4 v = *reinterpret_cast<const float4*>(&y[(size_t)row * 1024 + tid * 4]);
    float s = v.x + v.y + v.z + v.w;
    float ss = v.x * v.x + v.y * v.y + v.z * v.z + v.w * v.w;
    #pragma unroll
    for (int off = 32; off; off >>= 1) { s += __shfl_xor(s, off); ss += __shfl_xor(ss, off); }

    __shared__ float sbuf[4], ssbuf[4];
    int wv = tid >> 6;
    if ((tid & 63) == 0) { sbuf[wv] = s; ssbuf[wv] = ss; }
    __syncthreads();
    s = sbuf[0] + sbuf[1] + sbuf[2] + sbuf[3];
    ss = ssbuf[0] + ssbuf[1] + ssbuf[2] + ssbuf[3];

    float mu = s * (1.f / 1024.f);
    float var = ss * (1.f / 1024.f) - mu * mu;
    float rstd = rsqrtf(var + 1e-5f);

    bool pres = false;
    #pragma unroll
    for (int bb = 0; bb < 8; ++bb) pres = pres || (counts[bb * NBLK + k] > 0);

    float4 g4 = *reinterpret_cast<const float4*>(&ln_g[tid * 4]);
    float4 b4 = *reinterpret_cast<const float4*>(&ln_b[tid * 4]);
    float vals[4] = {v.x, v.y, v.z, v.w};
    float gs[4] = {g4.x, g4.y, g4.z, g4.w};
    float bs[4] = {b4.x, b4.y, b4.z, b4.w};
    float4 o;
    float* op = &o.x;
    #pragma unroll
    for (int j = 0; j < 4; ++j) {
        float t = (vals[j] - mu) * rstd * gs[j] + bs[j];
        t = (t > 0.f) ? t : expm1f(t);
        op[j] = pres ? t : 0.f;
    }
    *reinterpret_cast<float4*>(&outp[(size_t)row * 1024 + tid * 4]) = o;
}

// ---------------------------------------------------------------------------
extern "C" void kernel_launch(void* const* d_in, const int* in_sizes, int n_in,
                              void* d_out, int out_size, void* d_ws, size_t ws_size,
                              hipStream_t stream)
{
    const float* x      = (const float*)d_in[0];
    const int*   ct     = (const int*)d_in[1];
    const int*   bids   = (const int*)d_in[2];
    const unsigned char* pad = (const unsigned char*)d_in[3];
    const float* W1     = (const float*)d_in[4];
    const float* b1     = (const float*)d_in[5];
    const float* W2     = (const float*)d_in[6];
    const float* b2     = (const float*)d_in[7];
    const float* ct_emb = (const float*)d_in[8];
    const float* Wp     = (const float*)d_in[9];
    const float* bp     = (const float*)d_in[10];
    const float* ln_g   = (const float*)d_in[11];
    const float* ln_b   = (const float*)d_in[12];
    float* outF = (float*)d_out;

    char* ws = (char*)d_ws;
    bf16s* w1t    = (bf16s*)(ws + 0);          //  1,048,576
    bf16s* wpt    = (bf16s*)(ws + 1048576);    //  2,097,152 -> 3,145,728
    float* gate   = (float*)(ws + 3145728);    //    131,072 -> 3,276,800
    float* mblk   = (float*)(ws + 3276800);
    float* wscal  = (float*)(ws + 3280896);
    int*   counts = (int*)  (ws + 3284992);
    int*   offs   = (int*)  (ws + 3289088);
    int*   lists  = (int*)  (ws + 3293184);    //    131,072 -> 3,424,256
    float* wlist  = (float*)(ws + 3424256);    //    131,072 -> 3,555,328
    bf16s* pooled = (bf16s*)(ws + 3555328);    //  2,097,152 -> 5,652,480
    float* ybuf   = (float*)(ws + 5652480);    //  4,194,304 -> 9,846,784
    bf16s* xb     = (bf16s*)(ws + 9846784);    // 67,108,864 -> 76,955,648
    const int use_xb = (ws_size >= 76955648ull) ? 1 : 0;

    k_tcvt<<<dim3(16, 8), 256, 0, stream>>>(W1, w1t, HHALF);
    k_tcvt<<<dim3(16, 16), 256, 0, stream>>>(Wp, wpt, HDIM);
    k_gemm_gate<<<256, 512, 0, stream>>>(x, w1t, b1, W2, b2, gate, xb, use_xb);
    k_stats<<<1024, 64, 0, stream>>>(bids, pad, gate, ct, ct_emb, counts, mblk, wscal,
                                     outF + (size_t)8 * NBLK * HDIM);
    k_fill<<<1024, 64, 0, stream>>>(bids, pad, counts, gate, mblk, wscal, offs, lists, wlist);
    k_pool<<<1024, 256, 0, stream>>>(x, xb, use_xb, lists, wlist, counts, offs, pooled);
    k_gemm2<<<256, 256, 0, stream>>>(pooled, wpt, bp, ybuf);
    k_lnelu<<<1024, 256, 0, stream>>>(ybuf, ln_g, ln_b, counts, outF);
}

// Round 4
// 142.765 us; speedup vs baseline: 1.2962x; 1.2547x over previous
//
#include <hip/hip_runtime.h>

// (B,N,H,NB,NCT) = (8,4096,1024,128,33), H/2 = 512
#define NTOK 4096
#define HDIM 1024
#define HHALF 512
#define NBLK 128
#define CAP 256          // max members per (b,block); binomial(4096,1/128) max ~60

typedef __attribute__((ext_vector_type(8))) short short8;
typedef __attribute__((ext_vector_type(4))) float f32x4;
typedef short bf16s;

__device__ __forceinline__ short f2bf(float f) {
    unsigned u = __builtin_bit_cast(unsigned, f);
    u = (u + 0x7fffu + ((u >> 16) & 1u)) >> 16;   // RNE
    return (short)u;
}
__device__ __forceinline__ void gload_lds16(const void* g, void* l) {
    __builtin_amdgcn_global_load_lds(
        (const __attribute__((address_space(1))) unsigned int*)g,
        (__attribute__((address_space(3))) unsigned int*)l, 16, 0, 0);
}
__device__ __forceinline__ float fast_tanh(float v) {
    float e = __expf(2.0f * v);
    return 1.0f - 2.0f / (e + 1.0f);
}

// ---------------------------------------------------------------------------
// Tiled transpose+convert for both weights in one launch.
// by<8: w1t[n][k]=bf16(W1[k][n]) (n<512); else wpt[n][k]=bf16(Wp[k][n]).
// ---------------------------------------------------------------------------
__global__ void k_tcvt2(const float* __restrict__ W1, const float* __restrict__ Wp,
                        bf16s* __restrict__ w1t, bf16s* __restrict__ wpt) {
    __shared__ float tile[64][65];
    const int by = blockIdx.y;
    const float* in = (by < 8) ? W1 : Wp;
    bf16s* out = (by < 8) ? w1t : wpt;
    const int Nc = (by < 8) ? HHALF : HDIM;
    const int n0 = ((by < 8) ? by : (by - 8)) * 64;
    const int k0 = blockIdx.x * 64;
    const int tx = threadIdx.x & 63, ty = threadIdx.x >> 6;
    #pragma unroll
    for (int i = 0; i < 16; ++i) {
        int r = ty + i * 4;
        tile[r][tx] = in[(size_t)(k0 + r) * Nc + n0 + tx];
    }
    __syncthreads();
    #pragma unroll
    for (int i = 0; i < 16; ++i) {
        int r = ty + i * 4;
        out[(size_t)(n0 + r) * 1024 + k0 + tx] = f2bf(tile[tx][r]);
    }
}

// ---------------------------------------------------------------------------
// Gate GEMM stage 1: partial[ct][row] = sum over col-tile ct's 128 cols of
// tanh((x@W1)[row][c]+b1[c])*W2[c].
// M=32768, N=512 -> 4 col-tiles of 128. 128x128 tile, BK=32, 4 waves (2x2),
// wave tile 64x64, acc[4][4]. Single-buffered m97 structure; 1024 wgs.
// XCD-bijective swizzle keeps a row-panel's 4 col-tiles on one XCD (L2 reuse).
// ---------------------------------------------------------------------------
__global__ __launch_bounds__(256, 3) void k_gemm_h(
    const float* __restrict__ x, const bf16s* __restrict__ w1t,
    const float* __restrict__ b1, const float* __restrict__ w2,
    float* __restrict__ partial)
{
    __shared__ alignas(16) bf16s As[128 * 36];   // pad-36: conflict-free frag reads
    __shared__ alignas(16) bf16s Bs[128 * 32];   // linear (gll dest), swizzled src
    __shared__ float gp[2][128];

    const int tid = threadIdx.x;
    const int lane = tid & 63;
    const int wv = tid >> 6;
    const int wr = wv >> 1, wc = wv & 1;
    const int phys = blockIdx.x;
    const int logical = (phys & 7) * 128 + (phys >> 3);   // 1024 = 8*128 bijective
    const int row0 = (logical >> 2) * 128;
    const int col0 = (logical & 3) * 128;
    const int c0 = lane & 15, khalf = lane >> 4;

    const int ar = tid >> 1, ah = tid & 1;       // A stage: row, 16-col half
    const float* xsrc = &x[(size_t)(row0 + ar) * HDIM + ah * 16];

    const int brow = wv * 32 + (lane >> 2);      // B stage row (+ q*16)
    const int bj = lane & 3;

    f32x4 acc[4][4] = {};
    float4 pa0 = *reinterpret_cast<const float4*>(xsrc);
    float4 pa1 = *reinterpret_cast<const float4*>(xsrc + 4);
    float4 pa2 = *reinterpret_cast<const float4*>(xsrc + 8);
    float4 pa3 = *reinterpret_cast<const float4*>(xsrc + 12);

    for (int t = 0; t < 32; ++t) {
        const int kt = t * 32;
        __syncthreads();                          // all waves done reading LDS
        // stage A: f32->bf16 from prefetch regs, 2x ds_write_b128
        {
            short h[16] = {f2bf(pa0.x), f2bf(pa0.y), f2bf(pa0.z), f2bf(pa0.w),
                           f2bf(pa1.x), f2bf(pa1.y), f2bf(pa1.z), f2bf(pa1.w),
                           f2bf(pa2.x), f2bf(pa2.y), f2bf(pa2.z), f2bf(pa2.w),
                           f2bf(pa3.x), f2bf(pa3.y), f2bf(pa3.z), f2bf(pa3.w)};
            *reinterpret_cast<int4*>(&As[ar * 36 + ah * 16]) =
                *reinterpret_cast<const int4*>(&h[0]);
            *reinterpret_cast<int4*>(&As[ar * 36 + ah * 16 + 8]) =
                *reinterpret_cast<const int4*>(&h[8]);
        }
        // stage B: 2 gll per wave, source chunk XOR-swizzled
        #pragma unroll
        for (int q = 0; q < 2; ++q) {
            int r = brow + q * 16;
            int j = bj ^ ((r >> 1) & 3);
            gload_lds16(&w1t[(size_t)(col0 + r) * HDIM + kt + j * 8],
                        &Bs[(wv * 32 + q * 16) * 32 + lane * 8]);
        }
        __syncthreads();                          // tiles ready
        // prefetch next A f32 (hides under MFMA phase)
        if (t < 31) {
            pa0 = *reinterpret_cast<const float4*>(xsrc + kt + 32);
            pa1 = *reinterpret_cast<const float4*>(xsrc + kt + 36);
            pa2 = *reinterpret_cast<const float4*>(xsrc + kt + 40);
            pa3 = *reinterpret_cast<const float4*>(xsrc + kt + 44);
        }
        const int kk = khalf * 8;
        short8 av[4];
        #pragma unroll
        for (int mf = 0; mf < 4; ++mf)
            av[mf] = *reinterpret_cast<const short8*>(
                &As[(wr * 64 + mf * 16 + c0) * 36 + kk]);
        #pragma unroll
        for (int nf = 0; nf < 4; ++nf) {
            int rb = wc * 64 + nf * 16 + c0;
            short8 bv = *reinterpret_cast<const short8*>(
                &Bs[rb * 32 + ((khalf ^ ((rb >> 1) & 3)) * 8)]);
            #pragma unroll
            for (int mf = 0; mf < 4; ++mf)
                acc[mf][nf] = __builtin_amdgcn_mfma_f32_16x16x32_bf16(av[mf], bv, acc[mf][nf], 0, 0, 0);
        }
    }

    // epilogue: per-row partial dot of tanh(h)*W2 over this wave's 64 cols
    float b1v[4], w2v[4];
    #pragma unroll
    for (int nf = 0; nf < 4; ++nf) {
        int gc = col0 + wc * 64 + nf * 16 + c0;
        b1v[nf] = b1[gc];
        w2v[nf] = w2[gc];
    }
    #pragma unroll
    for (int mf = 0; mf < 4; ++mf) {
        #pragma unroll
        for (int reg = 0; reg < 4; ++reg) {
            float s = 0.f;
            #pragma unroll
            for (int nf = 0; nf < 4; ++nf)
                s += fast_tanh(acc[mf][nf][reg] + b1v[nf]) * w2v[nf];
            s += __shfl_xor(s, 1); s += __shfl_xor(s, 2);
            s += __shfl_xor(s, 4); s += __shfl_xor(s, 8);
            if (c0 == 0) gp[wc][wr * 64 + mf * 16 + khalf * 4 + reg] = s;
        }
    }
    __syncthreads();
    if (tid < 128)
        partial[(size_t)(logical & 3) * 32768 + row0 + tid] = gp[0][tid] + gp[1][tid];
}

// ---------------------------------------------------------------------------
// gate[row] = sum of 4 col-tile partials + b2
// ---------------------------------------------------------------------------
__global__ void k_gate_sum(const float* __restrict__ partial, const float* __restrict__ b2,
                           float* __restrict__ gate) {
    int i = (blockIdx.x * 256 + threadIdx.x) * 4;
    float4 p0 = *reinterpret_cast<const float4*>(&partial[i]);
    float4 p1 = *reinterpret_cast<const float4*>(&partial[32768 + i]);
    float4 p2 = *reinterpret_cast<const float4*>(&partial[65536 + i]);
    float4 p3 = *reinterpret_cast<const float4*>(&partial[98304 + i]);
    float bb = b2[0];
    float4 o = {p0.x + p1.x + p2.x + p3.x + bb, p0.y + p1.y + p2.y + p3.y + bb,
                p0.z + p1.z + p2.z + p3.z + bb, p0.w + p1.w + p2.w + p3.w + bb};
    *reinterpret_cast<float4*>(&gate[i]) = o;
}

// ---------------------------------------------------------------------------
// Single-pass per-(b,block): online-softmax stats + ordered member lists.
// One wave per (b,k). Writes counts/mblk/wscale, has_b, lists (fixed CAP).
// ---------------------------------------------------------------------------
__global__ void k_blocks(const int* __restrict__ block_ids, const unsigned char* __restrict__ pad,
                         const float* __restrict__ gate, const int* __restrict__ ct,
                         const float* __restrict__ ct_emb,
                         int* __restrict__ counts, float* __restrict__ mblk,
                         float* __restrict__ wscale, int* __restrict__ lists,
                         float* __restrict__ out_hasb)
{
    const int blk = blockIdx.x;
    const int b = blk >> 7, k = blk & 127;
    const int lane = threadIdx.x;
    const int base = b * NTOK;
    const int lbase = blk * CAP;
    const unsigned long long ltmask = (1ull << lane) - 1ull;

    float m = -__builtin_inff();
    float s = 0.f;
    int pos = 0;
    for (int t0 = 0; t0 < NTOK; t0 += 64) {
        int t = t0 + lane;
        bool mt = (block_ids[base + t] == k) && (pad[base + t] == 0);
        float g = gate[base + t];
        unsigned long long mask = __ballot(mt);
        if (mt) {
            int my = pos + __popcll(mask & ltmask);
            if (my < CAP) lists[lbase + my] = t;
            float mn = fmaxf(m, g);           // g finite -> mn finite
            s = s * __expf(m - mn) + __expf(g - mn);
            m = mn;
        }
        pos += __popcll(mask);
    }
    // combine lanes (safe against -inf lanes)
    #pragma unroll
    for (int off = 1; off < 64; off <<= 1) {
        float om = __shfl_xor(m, off);
        float os = __shfl_xor(s, off);
        float mn = fmaxf(m, om);
        float sa = (m == -__builtin_inff()) ? 0.f : s * __expf(m - mn);
        float sb = (om == -__builtin_inff()) ? 0.f : os * __expf(om - mn);
        s = sa + sb;
        m = mn;
    }
    if (lane == 0) {
        counts[blk] = pos;
        mblk[blk] = (pos > 0) ? m : 0.f;
        float mod = 1.0f + 0.1f * ct_emb[ct[b] * NBLK + k];
        wscale[blk] = (pos > 0 && s > 0.f) ? (mod / fmaxf(s, 1e-30f)) : 0.f;
        out_hasb[blk] = (pos > 0) ? 1.f : 0.f;
    }
}

// ---------------------------------------------------------------------------
// Pooling: pooled[b,k,:] = wscale * sum_n exp(gate[n]-m) * x[b,n,:]
// ---------------------------------------------------------------------------
__global__ void k_pool(const float* __restrict__ x, const float* __restrict__ gate,
                       const int* __restrict__ lists, const int* __restrict__ counts,
                       const float* __restrict__ mblk, const float* __restrict__ wscale,
                       bf16s* __restrict__ pooled)
{
    const int blk = blockIdx.x;
    const int b = blk >> 7;
    const int tid = threadIdx.x;
    const int base = b * NTOK;
    const int cnt = min(counts[blk], CAP);
    const int lbase = blk * CAP;
    const float m = mblk[blk], ws = wscale[blk];

    float4 acc = {0.f, 0.f, 0.f, 0.f};
    for (int i = 0; i < cnt; ++i) {
        int n = lists[lbase + i];
        float w = __expf(gate[base + n] - m);
        float4 xv = *reinterpret_cast<const float4*>(&x[(size_t)(base + n) * HDIM + tid * 4]);
        acc.x += w * xv.x; acc.y += w * xv.y; acc.z += w * xv.z; acc.w += w * xv.w;
    }
    short o[4] = {f2bf(acc.x * ws), f2bf(acc.y * ws), f2bf(acc.z * ws), f2bf(acc.w * ws)};
    *reinterpret_cast<int2*>(&pooled[(size_t)blk * HDIM + tid * 4]) =
        *reinterpret_cast<const int2*>(o);
}

// ---------------------------------------------------------------------------
// GEMM2: y = pooled @ Wp + bp. 1024^3. 64x64 tiles, 4 waves, dbuf + gll.
// ---------------------------------------------------------------------------
__global__ __launch_bounds__(256) void k_gemm2(
    const bf16s* __restrict__ pooled, const bf16s* __restrict__ wpt,
    const float* __restrict__ bp, float* __restrict__ y)
{
    __shared__ alignas(16) bf16s As[2][64 * 32];
    __shared__ alignas(16) bf16s Bs[2][64 * 32];
    const int tid = threadIdx.x;
    const int lane = tid & 63;
    const int wv = tid >> 6;
    const int wr = wv >> 1, wc = wv & 1;
    const int row0 = (blockIdx.x >> 4) * 64, col0 = (blockIdx.x & 15) * 64;
    const int c0 = lane & 15, khalf = lane >> 4;

    const int sr = wv * 16 + (lane >> 2);
    const int sj = (lane & 3) ^ ((sr >> 1) & 3);
    const int sdst = (wv * 16) * 32 + lane * 8;
    const bf16s* srcA = &pooled[(size_t)(row0 + sr) * 1024 + sj * 8];
    const bf16s* srcB = &wpt[(size_t)(col0 + sr) * 1024 + sj * 8];

    f32x4 acc[2][2] = {};

    gload_lds16(srcA, &As[0][sdst]);
    gload_lds16(srcB, &Bs[0][sdst]);
    __syncthreads();

    for (int t = 0; t < 32; ++t) {
        const int cur = t & 1;
        if (t < 31) {
            gload_lds16(srcA + (t + 1) * 32, &As[cur ^ 1][sdst]);
            gload_lds16(srcB + (t + 1) * 32, &Bs[cur ^ 1][sdst]);
        }
        #pragma unroll
        for (int mf = 0; mf < 2; ++mf) {
            int ra = wr * 32 + mf * 16 + c0;
            short8 av = *reinterpret_cast<const short8*>(
                &As[cur][ra * 32 + ((khalf ^ ((ra >> 1) & 3)) * 8)]);
            #pragma unroll
            for (int nf = 0; nf < 2; ++nf) {
                int rb = wc * 32 + nf * 16 + c0;
                short8 bv = *reinterpret_cast<const short8*>(
                    &Bs[cur][rb * 32 + ((khalf ^ ((rb >> 1) & 3)) * 8)]);
                acc[mf][nf] = __builtin_amdgcn_mfma_f32_16x16x32_bf16(av, bv, acc[mf][nf], 0, 0, 0);
            }
        }
        __syncthreads();
    }
    #pragma unroll
    for (int mf = 0; mf < 2; ++mf)
        #pragma unroll
        for (int nf = 0; nf < 2; ++nf)
            #pragma unroll
            for (int reg = 0; reg < 4; ++reg) {
                int grow = row0 + wr * 32 + mf * 16 + khalf * 4 + reg;
                int gcol = col0 + wc * 32 + nf * 16 + c0;
                y[(size_t)grow * 1024 + gcol] = acc[mf][nf][reg] + bp[gcol];
            }
}

// ---------------------------------------------------------------------------
// LayerNorm + ELU + present-mask.
// ---------------------------------------------------------------------------
__global__ void k_lnelu(const float* __restrict__ y, const float* __restrict__ ln_g,
                        const float* __restrict__ ln_b, const int* __restrict__ counts,
                        float* __restrict__ outp)
{
    const int row = blockIdx.x;
    const int k = row & 127;
    const int tid = threadIdx.x;

    float4 v = *reinterpret_cast<const float4*>(&y[(size_t)row * 1024 + tid * 4]);
    float s = v.x + v.y + v.z + v.w;
    float ss = v.x * v.x + v.y * v.y + v.z * v.z + v.w * v.w;
    #pragma unroll
    for (int off = 32; off; off >>= 1) { s += __shfl_xor(s, off); ss += __shfl_xor(ss, off); }

    __shared__ float sbuf[4], ssbuf[4];
    int wv = tid >> 6;
    if ((tid & 63) == 0) { sbuf[wv] = s; ssbuf[wv] = ss; }
    __syncthreads();
    s = sbuf[0] + sbuf[1] + sbuf[2] + sbuf[3];
    ss = ssbuf[0] + ssbuf[1] + ssbuf[2] + ssbuf[3];

    float mu = s * (1.f / 1024.f);
    float var = ss * (1.f / 1024.f) - mu * mu;
    float rstd = rsqrtf(var + 1e-5f);

    bool pres = false;
    #pragma unroll
    for (int bb = 0; bb < 8; ++bb) pres = pres || (counts[bb * NBLK + k] > 0);

    float4 g4 = *reinterpret_cast<const float4*>(&ln_g[tid * 4]);
    float4 b4 = *reinterpret_cast<const float4*>(&ln_b[tid * 4]);
    float vals[4] = {v.x, v.y, v.z, v.w};
    float gs[4] = {g4.x, g4.y, g4.z, g4.w};
    float bs[4] = {b4.x, b4.y, b4.z, b4.w};
    float4 o;
    float* op = &o.x;
    #pragma unroll
    for (int j = 0; j < 4; ++j) {
        float t = (vals[j] - mu) * rstd * gs[j] + bs[j];
        t = (t > 0.f) ? t : expm1f(t);
        op[j] = pres ? t : 0.f;
    }
    *reinterpret_cast<float4*>(&outp[(size_t)row * 1024 + tid * 4]) = o;
}

// ---------------------------------------------------------------------------
extern "C" void kernel_launch(void* const* d_in, const int* in_sizes, int n_in,
                              void* d_out, int out_size, void* d_ws, size_t ws_size,
                              hipStream_t stream)
{
    const float* x      = (const float*)d_in[0];
    const int*   ct     = (const int*)d_in[1];
    const int*   bids   = (const int*)d_in[2];
    const unsigned char* pad = (const unsigned char*)d_in[3];
    const float* W1     = (const float*)d_in[4];
    const float* b1     = (const float*)d_in[5];
    const float* W2     = (const float*)d_in[6];
    const float* b2     = (const float*)d_in[7];
    const float* ct_emb = (const float*)d_in[8];
    const float* Wp     = (const float*)d_in[9];
    const float* bp     = (const float*)d_in[10];
    const float* ln_g   = (const float*)d_in[11];
    const float* ln_b   = (const float*)d_in[12];
    float* outF = (float*)d_out;

    char* ws = (char*)d_ws;
    bf16s* w1t    = (bf16s*)(ws + 0);          //  1,048,576
    bf16s* wpt    = (bf16s*)(ws + 1048576);    //  2,097,152 -> 3,145,728
    float* gate   = (float*)(ws + 3145728);    //    131,072 -> 3,276,800
    float* part   = (float*)(ws + 3276800);    //    524,288 -> 3,801,088
    float* mblk   = (float*)(ws + 3801088);
    float* wscal  = (float*)(ws + 3805184);
    int*   counts = (int*)  (ws + 3809280);
    int*   lists  = (int*)  (ws + 3813376);    //  1,048,576 -> 4,861,952
    bf16s* pooled = (bf16s*)(ws + 4861952);    //  2,097,152 -> 6,959,104
    float* ybuf   = (float*)(ws + 6959104);    //  4,194,304 -> 11,153,408

    k_tcvt2<<<dim3(16, 24), 256, 0, stream>>>(W1, Wp, w1t, wpt);
    k_gemm_h<<<1024, 256, 0, stream>>>(x, w1t, b1, W2, part);
    k_gate_sum<<<32, 256, 0, stream>>>(part, b2, gate);
    k_blocks<<<1024, 64, 0, stream>>>(bids, pad, gate, ct, ct_emb, counts, mblk, wscal,
                                      lists, outF + (size_t)8 * NBLK * HDIM);
    k_pool<<<1024, 256, 0, stream>>>(x, gate, lists, counts, mblk, wscal, pooled);
    k_gemm2<<<256, 256, 0, stream>>>(pooled, wpt, bp, ybuf);
    k_lnelu<<<1024, 256, 0, stream>>>(ybuf, ln_g, ln_b, counts, outF);
}